// Round 2
// baseline (472.028 us; speedup 1.0000x reference)
//
#include <hip/hip_runtime.h>

#define SEQS_PER_WG 8
#define HID 128
#define NF 13
#define SLEN 128
#define NSEQ 2048
#define ZST 232            // f16 elems per z row (16B-aligned rows)
#define NTHREADS 512

typedef _Float16 half8 __attribute__((ext_vector_type(8)));
typedef float floatx4 __attribute__((ext_vector_type(4)));

__device__ __forceinline__ float sigm(float x)  { return __builtin_amdgcn_rcpf(1.0f + __expf(-x)); }
__device__ __forceinline__ float tanh_(float x) { return 1.0f - 2.0f * __builtin_amdgcn_rcpf(1.0f + __expf(2.0f * x)); }

// One LSTM gate step: NKS K-steps of MFMA from zbuf[P], elementwise, h -> zbuf[1-P].
// Each lane owns unit u, seqs at even rows lrow+0 / lrow+2.
#define GATE_STEP(NKS, BV, P)                                                          \
    do {                                                                               \
        half8 a_[5];                                                                   \
        _Pragma("unroll")                                                              \
        for (int ks = 0; ks < (NKS); ++ks)                                             \
            a_[ks] = *(const half8*)&zbuf[(P)][lcol * ZST + ks * 32 + quad * 8];       \
        floatx4 acc_[4];                                                               \
        _Pragma("unroll")                                                              \
        for (int g = 0; g < 4; ++g) {                                                  \
            float b_ = (BV)[g];                                                        \
            acc_[g] = (floatx4){b_, b_, b_, b_};                                       \
        }                                                                              \
        _Pragma("unroll")                                                              \
        for (int ks = 0; ks < (NKS); ++ks)                                             \
            _Pragma("unroll")                                                          \
            for (int g = 0; g < 4; ++g)                                                \
                acc_[g] = __builtin_amdgcn_mfma_f32_16x16x32_f16(                      \
                    a_[ks], Bf[g][ks], acc_[g], 0, 0, 0);                              \
        _Pragma("unroll")                                                              \
        for (int idx = 0; idx < 2; ++idx) {                                            \
            const int r_ = idx * 2;                                                    \
            float ii = sigm(acc_[0][r_]);                                              \
            float ff = sigm(acc_[1][r_]);                                              \
            float gg = tanh_(acc_[2][r_]);                                             \
            float oo = sigm(acc_[3][r_]);                                              \
            float c_ = ff * creg[idx] + ii * gg;                                       \
            creg[idx] = c_;                                                            \
            float h_ = oo * tanh_(c_);                                                 \
            hreg[idx] = h_;                                                            \
            zbuf[1 - (P)][(lrow + r_) * ZST + u] = (_Float16)h_;                       \
        }                                                                              \
    } while (0)

__global__ __launch_bounds__(NTHREADS)
void lstm_encdec_kernel(const float* __restrict__ X,
                        const float* __restrict__ W_ih,
                        const float* __restrict__ W_hh,
                        const float* __restrict__ b_ih,
                        const float* __restrict__ b_hh,
                        const float* __restrict__ W_fc,
                        const float* __restrict__ b_fc,
                        float* __restrict__ out)
{
    // z rows 0..15: seq s lives at row 2s (odd rows stay zero -> ghost MFMA rows).
    // cols 0..127 = h, cols 128..140 = x (padded to 160-K for the encoder).
    __shared__ _Float16 zbuf[2][16 * ZST];

    const int tid  = threadIdx.x;
    const int wave = tid >> 6;
    const int lane = tid & 63;
    const int quad = lane >> 4;
    const int lcol = lane & 15;
    const int lrow = quad * 4;
    const int u    = wave * 16 + lcol;     // hidden unit this lane owns
    const int seq0 = blockIdx.x * SEQS_PER_WG;

    // ---- encoder weight fragments: gate n = g*128 + u, 5 K-steps (4 of W_hh + 1 of W_ih pad) ----
    half8 Bf[4][5];
    float bias[4];
    #pragma unroll
    for (int g = 0; g < 4; ++g) {
        const int n = g * HID + u;
        #pragma unroll
        for (int ks = 0; ks < 4; ++ks) {
            const float* p = W_hh + n * HID + ks * 32 + quad * 8;
            half8 v;
            #pragma unroll
            for (int j = 0; j < 8; ++j) v[j] = (_Float16)p[j];
            Bf[g][ks] = v;
        }
        {
            half8 v;
            #pragma unroll
            for (int j = 0; j < 8; ++j) {
                int kk = quad * 8 + j;
                v[j] = (kk < NF) ? (_Float16)W_ih[n * NF + kk] : (_Float16)0.0f;
            }
            Bf[g][4] = v;
        }
        bias[g] = b_ih[n] + b_hh[n];
    }

    // ---- FC fragments (all waves hold them; FC runs round-robin) ----
    half8 Wfcf[4];
    float bfc = (lcol < NF) ? b_fc[lcol] : 0.0f;
    #pragma unroll
    for (int ks = 0; ks < 4; ++ks) {
        half8 v;
        #pragma unroll
        for (int j = 0; j < 8; ++j)
            v[j] = (lcol < NF) ? (_Float16)W_fc[lcol * HID + ks * 32 + quad * 8 + j]
                               : (_Float16)0.0f;
        Wfcf[ks] = v;
    }

    // ---- init LDS: zero both buffers, then x_0 into buffer 0 ----
    for (int i = tid; i < 2 * 16 * ZST; i += NTHREADS)
        ((_Float16*)zbuf)[i] = (_Float16)0.0f;
    __syncthreads();
    if (tid < SEQS_PER_WG * NF) {
        int s = tid / NF, f = tid - s * NF;
        zbuf[0][(2 * s) * ZST + HID + f] = (_Float16)X[(seq0 + s) * SLEN * NF + f];
    }
    __syncthreads();

    float creg[2] = {0.0f, 0.0f};
    float hreg[2];
    int p = 0;

    // ===================== encoder: 128 steps, 1 barrier/step =====================
    const bool xl = (tid < SEQS_PER_WG * NF);
    const int  xs = xl ? tid / NF : 0;
    const int  xf = xl ? tid - xs * NF : 0;
    for (int t = 0; t < SLEN; ++t) {
        const int tn = (t + 1 < SLEN) ? t + 1 : SLEN - 1;  // t=127 stages x0 for decoder step 1
        float xpre = 0.0f;
        if (xl) xpre = X[((seq0 + xs) * SLEN + tn) * NF + xf];

        GATE_STEP(5, bias, p);

        if (xl) zbuf[1 - p][(2 * xs) * ZST + HID + xf] = (_Float16)xpre;
        __syncthreads();
        p ^= 1;
    }

    // embeddings = h_n
    #pragma unroll
    for (int idx = 0; idx < 2; ++idx)
        out[(seq0 + quad * 2 + idx) * HID + u] = hreg[idx];

    // ===================== decoder step 1 (uses x0 + encoder weights) =====================
    GATE_STEP(5, bias, p);
    __syncthreads();
    p ^= 1;

    // ---- rebuild Bf[g][0..3] as W_dec = W_hh + W_ih @ W_fc, bias as b + W_ih @ b_fc ----
    #pragma unroll
    for (int g = 0; g < 4; ++g) {
        const int n = g * HID + u;
        float wih[NF];
        #pragma unroll
        for (int f = 0; f < NF; ++f) wih[f] = W_ih[n * NF + f];
        float bd = bias[g];
        #pragma unroll
        for (int f = 0; f < NF; ++f) bd += wih[f] * b_fc[f];
        bias[g] = bd;
        #pragma unroll
        for (int ks = 0; ks < 4; ++ks) {
            half8 v;
            #pragma unroll
            for (int j = 0; j < 8; ++j) {
                const int k = ks * 32 + quad * 8 + j;
                float val = W_hh[n * HID + k];
                #pragma unroll
                for (int f = 0; f < NF; ++f) val += wih[f] * W_fc[f * HID + k];
                v[j] = (_Float16)val;
            }
            Bf[g][ks] = v;
        }
    }

    // ===================== decoder steps 2..128 (folded h-recurrence) =====================
    float* dec = out + NSEQ * HID;
    for (int t = 1; t < SLEN; ++t) {
        // off-path: FC(h_t) -> dec slot t-1, round-robin wave, reads the stable buffer
        if (wave == (t & 7)) {
            half8 af[4];
            #pragma unroll
            for (int ks = 0; ks < 4; ++ks)
                af[ks] = *(const half8*)&zbuf[p][lcol * ZST + ks * 32 + quad * 8];
            floatx4 o = (floatx4){bfc, bfc, bfc, bfc};
            #pragma unroll
            for (int ks = 0; ks < 4; ++ks)
                o = __builtin_amdgcn_mfma_f32_16x16x32_f16(af[ks], Wfcf[ks], o, 0, 0, 0);
            if (lcol < NF) {
                #pragma unroll
                for (int idx = 0; idx < 2; ++idx) {
                    const int s = quad * 2 + idx;
                    dec[((seq0 + s) * SLEN + (t - 1)) * NF + lcol] = o[idx * 2];
                }
            }
        }

        GATE_STEP(4, bias, p);
        __syncthreads();
        p ^= 1;
    }

    // final FC(h_128) -> dec slot 127
    if (wave == 0) {
        half8 af[4];
        #pragma unroll
        for (int ks = 0; ks < 4; ++ks)
            af[ks] = *(const half8*)&zbuf[p][lcol * ZST + ks * 32 + quad * 8];
        floatx4 o = (floatx4){bfc, bfc, bfc, bfc};
        #pragma unroll
        for (int ks = 0; ks < 4; ++ks)
            o = __builtin_amdgcn_mfma_f32_16x16x32_f16(af[ks], Wfcf[ks], o, 0, 0, 0);
        if (lcol < NF) {
            #pragma unroll
            for (int idx = 0; idx < 2; ++idx) {
                const int s = quad * 2 + idx;
                dec[((seq0 + s) * SLEN + (SLEN - 1)) * NF + lcol] = o[idx * 2];
            }
        }
    }
}

extern "C" void kernel_launch(void* const* d_in, const int* in_sizes, int n_in,
                              void* d_out, int out_size, void* d_ws, size_t ws_size,
                              hipStream_t stream) {
    const float* X    = (const float*)d_in[0];
    const float* W_ih = (const float*)d_in[1];
    const float* W_hh = (const float*)d_in[2];
    const float* b_ih = (const float*)d_in[3];
    const float* b_hh = (const float*)d_in[4];
    const float* W_fc = (const float*)d_in[5];
    const float* b_fc = (const float*)d_in[6];
    float* out = (float*)d_out;

    lstm_encdec_kernel<<<NSEQ / SEQS_PER_WG, NTHREADS, 0, stream>>>(
        X, W_ih, W_hh, b_ih, b_hh, W_fc, b_fc, out);
}